// Round 7
// baseline (191.618 us; speedup 1.0000x reference)
//
#include <hip/hip_runtime.h>

#define SLOPE 0.1f
#define EPS 1e-5f

typedef __bf16 bf16x8 __attribute__((ext_vector_type(8)));
typedef unsigned short u16x8 __attribute__((ext_vector_type(8)));
typedef float f32x4 __attribute__((ext_vector_type(4)));
typedef unsigned u32x4 __attribute__((ext_vector_type(4)));

// ---- workspace layout ----
// float offsets on (float*)ws:
#define WS_ESC 0        // 32 : edge BN scale  (written by k2 last block)
#define WS_ESH 32       // 32 : edge BN shift
#define WS_CNT 64       // 1  : int completion counter (zeroed by k1)
#define WS_A 96         // 512 : dot(xn_i, ev[0:64])
#define WS_B 608        // 512 : dot(xn_j, ev[96:160])
#define WS_XN 1120      // 512*64 post-lrelu node feats
#define WS_NEWX 33888   // 512*64 pre-BN new_x
#define WS_P1B 66656    // 512*80 : b_h2[k] + x_i . W_h2[k][0:64]
#define WS_PART 107616  // 512 slots x 64 : edge BN partials (sum[0:32], sumsq[32:64])
// u16 offsets on (unsigned short*)ws (float end = 140384 -> u16 280768):
#define WSH_WB 280768   // 80*64 bf16: [n][0:32]=W_h2[n][64:96] (ea W), [n][32:64]=W_h2[n][96:128]
#define WSH_WB2 285888  // 80*32 bf16: W_h2[n][128:160]
#define WSH_WO 288448   // 32*96 bf16: W_eo[n][k], 0-padded to 96
#define WSH_XB 291520   // 512*64 bf16 copy of x
#define WSH_NE 324288   // 262144 edges * 16 u32 (col c | col c+16), bf16 pair packed

__device__ __forceinline__ float lrelu(float v) { return v > 0.f ? v : SLOPE * v; }
__device__ __forceinline__ unsigned short f2bf(float f) {
  unsigned x = __float_as_uint(f);
  return (unsigned short)((x + 0x7fffu + ((x >> 16) & 1u)) >> 16);
}
__device__ __forceinline__ float bf2f(unsigned short u) {
  return __uint_as_float(((unsigned)u) << 16);
}

// ---------------- K1 ----------------
// blocks 0..127 : xn + a/b scalars + bf16 copies (x, weights) + counter zero
// blocks 128..167 : P1 via MFMA  (M=512 x N=80, K=64)
__global__ void __launch_bounds__(256) k1(const float* __restrict__ x,
                                          const float* __restrict__ W_nu,
                                          const float* __restrict__ b_nu,
                                          const float* __restrict__ W_h2,
                                          const float* __restrict__ b_h2,
                                          const float* __restrict__ W_eo,
                                          const float* __restrict__ ev,
                                          float* ws) {
  int blk = blockIdx.x;
  int tid = threadIdx.x;
  unsigned short* wsh = (unsigned short*)ws;
  if (blk < 128) {
    __shared__ float wlds[64 * 65];
#pragma unroll
    for (int it = 0; it < 16; it++) {
      int idx = it * 256 + tid;
      wlds[(idx >> 6) * 65 + (idx & 63)] = W_nu[idx];
    }
    int gid = blk * 256 + tid;  // 0..32767
    wsh[WSH_XB + gid] = f2bf(x[gid]);
    if (gid < 5120) {
      wsh[WSH_WB + gid] = f2bf(W_h2[(gid >> 6) * 160 + 64 + (gid & 63)]);
    } else if (gid < 7680) {
      int idx = gid - 5120;
      wsh[WSH_WB2 + idx] = f2bf(W_h2[(idx >> 5) * 160 + 128 + (idx & 31)]);
    } else if (gid < 10752) {
      int idx = gid - 7680;
      int n = idx / 96, kk = idx - 96 * n;
      wsh[WSH_WO + idx] = (kk < 80) ? f2bf(W_eo[n * 80 + kk]) : (unsigned short)0;
    }
    if (gid == 0) *(int*)(ws + WS_CNT) = 0;
    __syncthreads();
    int i = blk * 4 + (tid >> 6);
    int c = tid & 63;
    float acc = b_nu[c];
    const float* xr = x + i * 64;
#pragma unroll 8
    for (int k = 0; k < 64; k++) acc += xr[k] * wlds[c * 65 + k];
    float xnv = lrelu(acc);
    ws[WS_XN + i * 64 + c] = xnv;
    float va = xnv * ev[c];
    float vb = xnv * ev[96 + c];
#pragma unroll
    for (int off = 32; off >= 1; off >>= 1) {
      va += __shfl_xor(va, off, 64);
      vb += __shfl_xor(vb, off, 64);
    }
    if (c == 0) { ws[WS_A + i] = va; ws[WS_B + i] = vb; }
  } else {
    // MFMA P1-GEMM: block covers 64 rows (bm) x 16 cols (bn) of N=80
    int b2 = blk - 128;             // 0..39
    int bm = b2 & 7, bn = b2 >> 3;  // M-tile of 64, N-tile of 16 (bn 0..4)
    int wave = tid >> 6, lane = tid & 63;
    int c16 = lane & 15, q = lane >> 4;
    int n = bn * 16 + c16;  // 0..79
    const float* wrow = W_h2 + n * 160;
    int mrow = bm * 64 + wave * 16 + c16;
    bf16x8 bfr[2], afr[2];
#pragma unroll
    for (int ks = 0; ks < 2; ks++) {
      const float* bs = wrow + ks * 32 + q * 8;
      const float* as = x + mrow * 64 + ks * 32 + q * 8;
      u16x8 ub, ua;
#pragma unroll
      for (int jj = 0; jj < 8; jj++) { ub[jj] = f2bf(bs[jj]); ua[jj] = f2bf(as[jj]); }
      bfr[ks] = __builtin_bit_cast(bf16x8, ub);
      afr[ks] = __builtin_bit_cast(bf16x8, ua);
    }
    float bias = b_h2[n];
    f32x4 acc = {bias, bias, bias, bias};
    acc = __builtin_amdgcn_mfma_f32_16x16x32_bf16(afr[0], bfr[0], acc, 0, 0, 0);
    acc = __builtin_amdgcn_mfma_f32_16x16x32_bf16(afr[1], bfr[1], acc, 0, 0, 0);
#pragma unroll
    for (int r = 0; r < 4; r++) {
      int mm = bm * 64 + wave * 16 + q * 4 + r;
      ws[WS_P1B + mm * 80 + n] = acc[r];
    }
  }
}

// ---------------- K2: fully fused edge row ----------------
// block = one row i (512 j); 8 waves x 4 sequential 16-edge tiles.
// GEMM1 over K=96 ([ea | x_j]) -> h -> GEMM2 -> ne(bf16 packed) + BN partials +
// scores -> softmax -> att@xn -> new_x. Last block reduces partials -> esc/esh.
__global__ void __launch_bounds__(512, 4) k2(const float* __restrict__ ea,
                                             const int* __restrict__ mask,
                                             const float* __restrict__ b_eo,
                                             const float* __restrict__ ev,
                                             const float* __restrict__ bn_e_w,
                                             const float* __restrict__ bn_e_b,
                                             float* ws) {
  __shared__ unsigned short ht[128 * 104];  // 8 waves * 16 rows, stride 104 u16
  __shared__ float srow[512];               // scores -> att -> (last blk) totals
  __shared__ float mlds[512];
  __shared__ float p1s[80];
  __shared__ float wred[2][8][32];
  __shared__ float nx[8][64];
  __shared__ float red[8];
  __shared__ int lastf;
  int tid = threadIdx.x;
  int w = tid >> 6, lane = tid & 63;
  int c16 = lane & 15, q = lane >> 4;
  int i = blockIdx.x;
  const unsigned short* wsh = (const unsigned short*)ws;
  unsigned* ne32 = (unsigned*)((unsigned short*)ws + WSH_NE);

  mlds[tid] = mask[i * 512 + tid] ? 1.f : 0.f;
  if (tid < 80) p1s[tid] = ws[WS_P1B + i * 80 + tid];

  // persistent B-frags for GEMM1 (3 K-chunks x 5 N-tiles)
  bf16x8 wb0[5], wb1[5], wb2f[5];
#pragma unroll
  for (int t = 0; t < 5; t++) {
    int n = t * 16 + c16;
    wb0[t] = __builtin_bit_cast(bf16x8, *(const u16x8*)(wsh + WSH_WB + n * 64 + q * 8));
    wb1[t] = __builtin_bit_cast(bf16x8,
                                *(const u16x8*)(wsh + WSH_WB + n * 64 + 32 + q * 8));
    wb2f[t] = __builtin_bit_cast(bf16x8, *(const u16x8*)(wsh + WSH_WB2 + n * 32 + q * 8));
  }
  float beo0 = b_eo[c16], beo1 = b_eo[16 + c16];
  float eve0 = ev[64 + c16], eve1 = ev[80 + c16];
  float a_i = ws[WS_A + i];
  __syncthreads();  // mlds/p1s staged

  float scs0 = 0.f, scss0 = 0.f, scs1 = 0.f, scss1 = 0.f;
#pragma unroll 1
  for (int mt = 0; mt < 4; mt++) {
    int jb = w * 64 + mt * 16;
    // A-frags: chunk0 = ea (f2bf), chunk1/2 = bf16 x_j (direct 16B loads)
    bf16x8 af0;
    {
      const float* src = ea + (i * 512 + jb + c16) * 32 + q * 8;
      u16x8 u;
#pragma unroll
      for (int jj = 0; jj < 8; jj++) u[jj] = f2bf(src[jj]);
      af0 = __builtin_bit_cast(bf16x8, u);
    }
    bf16x8 af1 = __builtin_bit_cast(
        bf16x8, *(const u16x8*)(wsh + WSH_XB + (jb + c16) * 64 + q * 8));
    bf16x8 af2 = __builtin_bit_cast(
        bf16x8, *(const u16x8*)(wsh + WSH_XB + (jb + c16) * 64 + 32 + q * 8));
    f32x4 acc[5];
#pragma unroll
    for (int t = 0; t < 5; t++) {
      float p1v = p1s[t * 16 + c16];
      acc[t] = {p1v, p1v, p1v, p1v};
    }
#pragma unroll
    for (int t = 0; t < 5; t++)
      acc[t] = __builtin_amdgcn_mfma_f32_16x16x32_bf16(af0, wb0[t], acc[t], 0, 0, 0);
#pragma unroll
    for (int t = 0; t < 5; t++)
      acc[t] = __builtin_amdgcn_mfma_f32_16x16x32_bf16(af1, wb1[t], acc[t], 0, 0, 0);
#pragma unroll
    for (int t = 0; t < 5; t++)
      acc[t] = __builtin_amdgcn_mfma_f32_16x16x32_bf16(af2, wb2f[t], acc[t], 0, 0, 0);
    // lrelu -> ht (same-wave stripe; no barrier)
#pragma unroll
    for (int t = 0; t < 5; t++)
#pragma unroll
      for (int r = 0; r < 4; r++)
        ht[(w * 16 + q * 4 + r) * 104 + t * 16 + c16] = f2bf(lrelu(acc[t][r]));
    // GEMM2 (wo frags reloaded per tile to cap register pressure; L2-hot)
    f32x4 acc2[2] = {{0.f, 0.f, 0.f, 0.f}, {0.f, 0.f, 0.f, 0.f}};
    int hrow = w * 16 + c16;
#pragma unroll
    for (int s = 0; s < 3; s++) {
      int kk = s * 32 + q * 8;
      u16x8 hb = {0, 0, 0, 0, 0, 0, 0, 0};
      if (kk < 80) hb = *(const u16x8*)&ht[hrow * 104 + kk];
      bf16x8 ha = __builtin_bit_cast(bf16x8, hb);
      bf16x8 wo0 = __builtin_bit_cast(
          bf16x8, *(const u16x8*)(wsh + WSH_WO + c16 * 96 + s * 32 + q * 8));
      bf16x8 wo1 = __builtin_bit_cast(
          bf16x8, *(const u16x8*)(wsh + WSH_WO + (16 + c16) * 96 + s * 32 + q * 8));
      acc2[0] = __builtin_amdgcn_mfma_f32_16x16x32_bf16(ha, wo0, acc2[0], 0, 0, 0);
      acc2[1] = __builtin_amdgcn_mfma_f32_16x16x32_bf16(ha, wo1, acc2[1], 0, 0, 0);
    }
    // epilogue
    float se[4];
#pragma unroll
    for (int r = 0; r < 4; r++) {
      int jl = jb + q * 4 + r;
      float mf = mlds[jl];
      float v0 = lrelu(acc2[0][r] + beo0) * mf;
      float v1 = lrelu(acc2[1][r] + beo1) * mf;
      scs0 += v0; scss0 += v0 * v0;
      scs1 += v1; scss1 += v1 * v1;
      ne32[(i * 512 + jl) * 16 + c16] = (unsigned)f2bf(v0) | ((unsigned)f2bf(v1) << 16);
      float s = v0 * eve0 + v1 * eve1;
#pragma unroll
      for (int off = 8; off >= 1; off >>= 1) s += __shfl_xor(s, off, 64);
      se[r] = s;
    }
    if (c16 < 4) {
      int jl = jb + q * 4 + c16;
      float s = (c16 == 0) ? se[0] : (c16 == 1) ? se[1] : (c16 == 2) ? se[2] : se[3];
      srow[jl] = lrelu(a_i + ws[WS_B + jl] + s);
    }
  }
  // col stats: reduce over q, stash per wave
  scs0 += __shfl_xor(scs0, 16, 64); scs0 += __shfl_xor(scs0, 32, 64);
  scss0 += __shfl_xor(scss0, 16, 64); scss0 += __shfl_xor(scss0, 32, 64);
  scs1 += __shfl_xor(scs1, 16, 64); scs1 += __shfl_xor(scs1, 32, 64);
  scss1 += __shfl_xor(scss1, 16, 64); scss1 += __shfl_xor(scss1, 32, 64);
  if (q == 0) {
    wred[0][w][c16] = scs0; wred[0][w][16 + c16] = scs1;
    wred[1][w][c16] = scss0; wred[1][w][16 + c16] = scss1;
  }
  __syncthreads();  // srow + wred complete
  if (tid < 64) {
    int half = tid >> 5, col = tid & 31;
    float v = 0.f;
#pragma unroll
    for (int ww = 0; ww < 8; ww++) v += wred[half][ww][col];
    ws[WS_PART + i * 64 + tid] = v;  // slot owned by this block, no atomics
  }
  // softmax (no max-subtraction: scores bounded small; shift-invariant)
  float p = __expf(srow[tid]);
  float sm = p;
#pragma unroll
  for (int off = 32; off >= 1; off >>= 1) sm += __shfl_xor(sm, off, 64);
  if (lane == 0) red[w] = sm;
  __syncthreads();
  float tot = red[0] + red[1] + red[2] + red[3] + red[4] + red[5] + red[6] + red[7];
  srow[tid] = p * (1.f / tot) * mlds[tid];  // att
  // att @ xn : wave w covers j in [w*64, (w+1)*64)
  float accv = 0.f;
#pragma unroll 4
  for (int u = 0; u < 64; u++) {
    int j = w * 64 + u;
    accv += srow[j] * ws[WS_XN + j * 64 + lane];
  }
  nx[w][lane] = accv;
  __syncthreads();
  if (tid < 64) {
    float s = 0.f;
#pragma unroll
    for (int ww = 0; ww < 8; ww++) s += nx[ww][tid];
    ws[WS_NEWX + i * 64 + tid] = s;
  }
  // ---- last-block: reduce edge-BN partials -> esc/esh ----
  if (tid == 0) {
    __threadfence();
    lastf = (atomicAdd((int*)(ws + WS_CNT), 1) == 511);
  }
  __syncthreads();
  if (lastf) {
    __threadfence();
    int g = tid >> 6, c = tid & 63;
    float a = 0.f;
    for (int s = g; s < 512; s += 8) a += ws[WS_PART + s * 64 + c];
    nx[g][c] = a;
    __syncthreads();
    if (tid < 64) {
      float t = 0.f;
#pragma unroll
      for (int g2 = 0; g2 < 8; g2++) t += nx[g2][tid];
      srow[tid] = t;
    }
    __syncthreads();
    if (tid < 32) {
      float mean = srow[tid] * (1.f / 262144.f);
      float var = srow[tid + 32] * (1.f / 262144.f) - mean * mean;
      float s = bn_e_w[tid] * rsqrtf(fmaxf(var, 0.f) + EPS);
      ws[WS_ESC + tid] = s;
      ws[WS_ESH + tid] = bn_e_b[tid] - mean * s;
    }
  }
}

// ---------------- K5: node BN (blocks 0..7, redundant stats) + edge BN apply ----------------
__global__ void __launch_bounds__(256) k5(const float* __restrict__ bn_n_w,
                                          const float* __restrict__ bn_n_b,
                                          const float* __restrict__ ws,
                                          float* __restrict__ out) {
  int blk = blockIdx.x, tid = threadIdx.x;
  if (blk < 8) {
    __shared__ float s1[4][64], s2[4][64], scl[64], sh[64];
    int c = tid & 63, g = tid >> 6;
    float a = 0.f, b = 0.f;
#pragma unroll 4
    for (int u = 0; u < 128; u++) {
      float v = ws[WS_NEWX + (g * 128 + u) * 64 + c];
      a += v;
      b += v * v;
    }
    s1[g][c] = a;
    s2[g][c] = b;
    __syncthreads();
    if (tid < 64) {
      float sum = s1[0][tid] + s1[1][tid] + s1[2][tid] + s1[3][tid];
      float ssq = s2[0][tid] + s2[1][tid] + s2[2][tid] + s2[3][tid];
      float mean = sum * (1.f / 512.f);
      float var = ssq * (1.f / 512.f) - mean * mean;
      float s = bn_n_w[tid] * rsqrtf(fmaxf(var, 0.f) + EPS);
      scl[tid] = s;
      sh[tid] = bn_n_b[tid] - mean * s;
    }
    __syncthreads();
#pragma unroll 4
    for (int u = 0; u < 16; u++) {
      int idx = blk * 4096 + u * 256 + tid;
      int c2 = idx & 63;
      out[idx] = ws[WS_NEWX + idx] * scl[c2] + sh[c2];
    }
  } else {
    const unsigned* ne32 = (const unsigned*)((const unsigned short*)ws + WSH_NE);
    int b4 = ((blk - 8) * 256 + tid) * 4;  // u32 index
    u32x4 raw = *(const u32x4*)(ne32 + b4);
    int e32 = (b4 >> 4) * 32;
    int cb = b4 & 15;  // 0,4,8,12
    f32x4 esc0 = *(const f32x4*)(ws + WS_ESC + cb);
    f32x4 esc1 = *(const f32x4*)(ws + WS_ESC + 16 + cb);
    f32x4 esh0 = *(const f32x4*)(ws + WS_ESH + cb);
    f32x4 esh1 = *(const f32x4*)(ws + WS_ESH + 16 + cb);
    f32x4 lo, hi;
#pragma unroll
    for (int u = 0; u < 4; u++) {
      lo[u] = bf2f((unsigned short)(raw[u] & 0xffffu)) * esc0[u] + esh0[u];
      hi[u] = bf2f((unsigned short)(raw[u] >> 16)) * esc1[u] + esh1[u];
    }
    float* oe = out + 32768;
    *(f32x4*)(oe + e32 + cb) = lo;
    *(f32x4*)(oe + e32 + 16 + cb) = hi;
  }
}

extern "C" void kernel_launch(void* const* d_in, const int* in_sizes, int n_in,
                              void* d_out, int out_size, void* d_ws, size_t ws_size,
                              hipStream_t stream) {
  const float* x = (const float*)d_in[0];
  const float* ea = (const float*)d_in[1];
  const int* mask = (const int*)d_in[2];
  const float* Wnu = (const float*)d_in[3];
  const float* bnu = (const float*)d_in[4];
  const float* Wh2 = (const float*)d_in[5];
  const float* bh2 = (const float*)d_in[6];
  const float* Weo = (const float*)d_in[7];
  const float* beo = (const float*)d_in[8];
  const float* ev = (const float*)d_in[9];
  const float* bnw = (const float*)d_in[10];
  const float* bnb = (const float*)d_in[11];
  const float* bew = (const float*)d_in[12];
  const float* beb = (const float*)d_in[13];
  float* ws = (float*)d_ws;
  float* out = (float*)d_out;

  k1<<<168, 256, 0, stream>>>(x, Wnu, bnu, Wh2, bh2, Weo, ev, ws);
  k2<<<512, 512, 0, stream>>>(ea, mask, beo, ev, bew, beb, ws);
  k5<<<4104, 256, 0, stream>>>(bnw, bnb, ws, out);
}

// Round 8
// 189.110 us; speedup vs baseline: 1.0133x; 1.0133x over previous
//
#include <hip/hip_runtime.h>

#define SLOPE 0.1f
#define EPS 1e-5f

typedef __bf16 bf16x8 __attribute__((ext_vector_type(8)));
typedef unsigned short u16x8 __attribute__((ext_vector_type(8)));
typedef float f32x4 __attribute__((ext_vector_type(4)));
typedef unsigned u32x4 __attribute__((ext_vector_type(4)));

// ---- workspace layout ----
// float offsets on (float*)ws:
#define WS_ESC 0        // 32 : edge BN scale (written by k3)
#define WS_ESH 32       // 32 : edge BN shift
#define WS_A 64         // 512 : dot(xn_i, ev[0:64])
#define WS_B 576        // 512 : dot(xn_j, ev[96:160])
#define WS_XN 1088      // 512*64 post-lrelu node feats
#define WS_NEWX 33856   // 512*64 pre-BN new_x
#define WS_P1B 66624    // 512*80 : b_h2[k] + x_i . W_h2[k][0:64]
#define WS_PART 107584  // 512 slots x 64 : edge BN partials (sum[0:32], sumsq[32:64])
// u16 offsets on (unsigned short*)ws (float end 140352 -> u16 280704).
// Weight tables stored FRAG-MAJOR: element (t, lane l, jj) at [t*512 + l*8 + jj],
// meaning value for MFMA B-frag: n = t*16 + (l&15), k = (l>>4)*8 + jj.
#define WSH_WB 280704   // 2*2560 : GEMM1 B chunks 0,1  (W_h2 cols 64:96, 96:128)
#define WSH_WB2 285824  // 2560   : GEMM1 B chunk 2     (W_h2 cols 128:160)
#define WSH_WO 288384   // 3072   : GEMM2 B (W_eo, k padded to 96): idx t2*1536+s*512+l*8+jj
#define WSH_XB 291456   // 512*64 bf16 copy of x (row-major)
#define WSH_NE 324224   // 262144 edges * 16 u32 (col c | col c+16), bf16 pair packed

__device__ __forceinline__ float lrelu(float v) { return v > 0.f ? v : SLOPE * v; }
__device__ __forceinline__ unsigned short f2bf(float f) {
  unsigned x = __float_as_uint(f);
  return (unsigned short)((x + 0x7fffu + ((x >> 16) & 1u)) >> 16);
}
__device__ __forceinline__ float bf2f(unsigned short u) {
  return __uint_as_float(((unsigned)u) << 16);
}

// ---------------- K1 ----------------
// blocks 0..127 : xn + a/b scalars + bf16 copies (x, frag-major weights)
// blocks 128..167 : P1 via MFMA  (M=512 x N=80, K=64)
__global__ void __launch_bounds__(256) k1(const float* __restrict__ x,
                                          const float* __restrict__ W_nu,
                                          const float* __restrict__ b_nu,
                                          const float* __restrict__ W_h2,
                                          const float* __restrict__ b_h2,
                                          const float* __restrict__ W_eo,
                                          const float* __restrict__ ev,
                                          float* ws) {
  int blk = blockIdx.x;
  int tid = threadIdx.x;
  unsigned short* wsh = (unsigned short*)ws;
  if (blk < 128) {
    __shared__ float wlds[64 * 65];
#pragma unroll
    for (int it = 0; it < 16; it++) {
      int idx = it * 256 + tid;
      wlds[(idx >> 6) * 65 + (idx & 63)] = W_nu[idx];
    }
    int gid = blk * 256 + tid;  // 0..32767
    wsh[WSH_XB + gid] = f2bf(x[gid]);
    if (gid < 5120) {
      // GEMM1 B chunks 0,1 (frag-major)
      int c = gid / 2560, r = gid - c * 2560;
      int t = r >> 9, l = (r >> 3) & 63, jj = r & 7;
      int n = t * 16 + (l & 15);
      int k = (l >> 4) * 8 + jj + c * 32;
      wsh[WSH_WB + gid] = f2bf(W_h2[n * 160 + 64 + k]);
    } else if (gid < 7680) {
      int idx = gid - 5120;
      int t = idx >> 9, l = (idx >> 3) & 63, jj = idx & 7;
      int n = t * 16 + (l & 15);
      int k = (l >> 4) * 8 + jj;
      wsh[WSH_WB2 + idx] = f2bf(W_h2[n * 160 + 128 + k]);
    } else if (gid < 10752) {
      int idx = gid - 7680;
      int t2 = idx / 1536, r2 = idx - t2 * 1536;
      int s = r2 >> 9, l = (r2 >> 3) & 63, jj = r2 & 7;
      int n = t2 * 16 + (l & 15);
      int k = s * 32 + (l >> 4) * 8 + jj;
      wsh[WSH_WO + idx] = (k < 80) ? f2bf(W_eo[n * 80 + k]) : (unsigned short)0;
    }
    __syncthreads();
    int i = blk * 4 + (tid >> 6);
    int c = tid & 63;
    float acc = b_nu[c];
    const float* xr = x + i * 64;
#pragma unroll 8
    for (int k = 0; k < 64; k++) acc += xr[k] * wlds[c * 65 + k];
    float xnv = lrelu(acc);
    ws[WS_XN + i * 64 + c] = xnv;
    float va = xnv * ev[c];
    float vb = xnv * ev[96 + c];
#pragma unroll
    for (int off = 32; off >= 1; off >>= 1) {
      va += __shfl_xor(va, off, 64);
      vb += __shfl_xor(vb, off, 64);
    }
    if (c == 0) { ws[WS_A + i] = va; ws[WS_B + i] = vb; }
  } else {
    // MFMA P1-GEMM: block covers 64 rows (bm) x 16 cols (bn) of N=80
    int b2 = blk - 128;             // 0..39
    int bm = b2 & 7, bn = b2 >> 3;  // M-tile of 64, N-tile of 16
    int wave = tid >> 6, lane = tid & 63;
    int c16 = lane & 15, q = lane >> 4;
    int n = bn * 16 + c16;  // 0..79
    const float* wrow = W_h2 + n * 160;
    int mrow = bm * 64 + wave * 16 + c16;
    bf16x8 bfr[2], afr[2];
#pragma unroll
    for (int ks = 0; ks < 2; ks++) {
      const float* bs = wrow + ks * 32 + q * 8;
      const float* as = x + mrow * 64 + ks * 32 + q * 8;
      u16x8 ub, ua;
#pragma unroll
      for (int jj = 0; jj < 8; jj++) { ub[jj] = f2bf(bs[jj]); ua[jj] = f2bf(as[jj]); }
      bfr[ks] = __builtin_bit_cast(bf16x8, ub);
      afr[ks] = __builtin_bit_cast(bf16x8, ua);
    }
    float bias = b_h2[n];
    f32x4 acc = {bias, bias, bias, bias};
    acc = __builtin_amdgcn_mfma_f32_16x16x32_bf16(afr[0], bfr[0], acc, 0, 0, 0);
    acc = __builtin_amdgcn_mfma_f32_16x16x32_bf16(afr[1], bfr[1], acc, 0, 0, 0);
#pragma unroll
    for (int r = 0; r < 4; r++) {
      int mm = bm * 64 + wave * 16 + q * 4 + r;
      ws[WS_P1B + mm * 80 + n] = acc[r];
    }
  }
}

// ---------------- K2: fully fused edge row ----------------
// block = one row i (512 j); 8 waves x 4 sequential 16-edge tiles.
// GEMM1 over K=96 ([ea | x_j]) -> h -> GEMM2 -> ne(bf16 packed) + BN partials +
// scores -> softmax -> att@xn -> new_x.  All B-frags served from LDS (frag-major,
// conflict-free ds_read_b128) to keep VGPR <= 128 at 2 blocks/CU without spills.
__global__ void __launch_bounds__(512, 4) k2(const float* __restrict__ ea,
                                             const int* __restrict__ mask,
                                             const float* __restrict__ b_eo,
                                             const float* __restrict__ ev,
                                             float* ws) {
  __shared__ unsigned short wlds[10752];    // [ch0|ch1|ch2|wo] frag-major
  __shared__ unsigned short ht[128 * 104];  // 8 waves * 16 rows, stride 104 u16
  __shared__ float srow[512];               // scores -> att
  __shared__ float mlds[512];
  __shared__ float blds[512];
  __shared__ float p1s[80];
  __shared__ float wred[2][8][32];
  __shared__ float nx[8][64];
  __shared__ float red[8];
  int tid = threadIdx.x;
  int w = tid >> 6, lane = tid & 63;
  int c16 = lane & 15, q = lane >> 4;
  int i = blockIdx.x;
  const unsigned short* wsh = (const unsigned short*)ws;
  unsigned* ne32 = (unsigned*)((unsigned short*)ws + WSH_NE);

  // stage all weight frags: contiguous 10752 u16 = 1344 x 16B chunks
#pragma unroll
  for (int it = 0; it < 3; it++) {
    int idx = it * 512 + tid;
    if (idx < 1344)
      *(u16x8*)&wlds[idx * 8] = *(const u16x8*)(wsh + WSH_WB + idx * 8);
  }
  mlds[tid] = mask[i * 512 + tid] ? 1.f : 0.f;
  blds[tid] = ws[WS_B + tid];
  if (tid < 80) p1s[tid] = ws[WS_P1B + i * 80 + tid];
  float beo0 = b_eo[c16], beo1 = b_eo[16 + c16];
  float eve0 = ev[64 + c16], eve1 = ev[80 + c16];
  float a_i = ws[WS_A + i];
  __syncthreads();

  float scs0 = 0.f, scss0 = 0.f, scs1 = 0.f, scss1 = 0.f;
#pragma unroll 1
  for (int mt = 0; mt < 4; mt++) {
    int jb = w * 64 + mt * 16;
    // A-frags: chunk0 = ea (f2bf), chunk1/2 = bf16 x_j (direct 16B loads)
    bf16x8 af0;
    {
      const float* src = ea + (i * 512 + jb + c16) * 32 + q * 8;
      u16x8 u;
#pragma unroll
      for (int jj = 0; jj < 8; jj++) u[jj] = f2bf(src[jj]);
      af0 = __builtin_bit_cast(bf16x8, u);
    }
    bf16x8 af1 = __builtin_bit_cast(
        bf16x8, *(const u16x8*)(wsh + WSH_XB + (jb + c16) * 64 + q * 8));
    bf16x8 af2 = __builtin_bit_cast(
        bf16x8, *(const u16x8*)(wsh + WSH_XB + (jb + c16) * 64 + 32 + q * 8));
    f32x4 acc[5];
#pragma unroll
    for (int t = 0; t < 5; t++) {
      float p1v = p1s[t * 16 + c16];
      acc[t] = {p1v, p1v, p1v, p1v};
    }
#pragma unroll
    for (int t = 0; t < 5; t++) {
      bf16x8 wb = __builtin_bit_cast(bf16x8, *(const u16x8*)&wlds[t * 512 + lane * 8]);
      acc[t] = __builtin_amdgcn_mfma_f32_16x16x32_bf16(af0, wb, acc[t], 0, 0, 0);
    }
#pragma unroll
    for (int t = 0; t < 5; t++) {
      bf16x8 wb =
          __builtin_bit_cast(bf16x8, *(const u16x8*)&wlds[2560 + t * 512 + lane * 8]);
      acc[t] = __builtin_amdgcn_mfma_f32_16x16x32_bf16(af1, wb, acc[t], 0, 0, 0);
    }
#pragma unroll
    for (int t = 0; t < 5; t++) {
      bf16x8 wb =
          __builtin_bit_cast(bf16x8, *(const u16x8*)&wlds[5120 + t * 512 + lane * 8]);
      acc[t] = __builtin_amdgcn_mfma_f32_16x16x32_bf16(af2, wb, acc[t], 0, 0, 0);
    }
    // lrelu -> ht (same-wave stripe; no barrier)
#pragma unroll
    for (int t = 0; t < 5; t++)
#pragma unroll
      for (int r = 0; r < 4; r++)
        ht[(w * 16 + q * 4 + r) * 104 + t * 16 + c16] = f2bf(lrelu(acc[t][r]));
    // GEMM2
    f32x4 acc2[2] = {{0.f, 0.f, 0.f, 0.f}, {0.f, 0.f, 0.f, 0.f}};
    int hrow = w * 16 + c16;
#pragma unroll
    for (int s = 0; s < 3; s++) {
      int kk = s * 32 + q * 8;
      u16x8 hb = {0, 0, 0, 0, 0, 0, 0, 0};
      if (kk < 80) hb = *(const u16x8*)&ht[hrow * 104 + kk];
      bf16x8 ha = __builtin_bit_cast(bf16x8, hb);
      bf16x8 wo0 = __builtin_bit_cast(
          bf16x8, *(const u16x8*)&wlds[7680 + s * 512 + lane * 8]);
      bf16x8 wo1 = __builtin_bit_cast(
          bf16x8, *(const u16x8*)&wlds[7680 + 1536 + s * 512 + lane * 8]);
      acc2[0] = __builtin_amdgcn_mfma_f32_16x16x32_bf16(ha, wo0, acc2[0], 0, 0, 0);
      acc2[1] = __builtin_amdgcn_mfma_f32_16x16x32_bf16(ha, wo1, acc2[1], 0, 0, 0);
    }
    // epilogue
    float se[4];
#pragma unroll
    for (int r = 0; r < 4; r++) {
      int jl = jb + q * 4 + r;
      float mf = mlds[jl];
      float v0 = lrelu(acc2[0][r] + beo0) * mf;
      float v1 = lrelu(acc2[1][r] + beo1) * mf;
      scs0 += v0; scss0 += v0 * v0;
      scs1 += v1; scss1 += v1 * v1;
      ne32[(i * 512 + jl) * 16 + c16] = (unsigned)f2bf(v0) | ((unsigned)f2bf(v1) << 16);
      float s = v0 * eve0 + v1 * eve1;
#pragma unroll
      for (int off = 8; off >= 1; off >>= 1) s += __shfl_xor(s, off, 64);
      se[r] = s;
    }
    if (c16 < 4) {
      int jl = jb + q * 4 + c16;
      float s = (c16 == 0) ? se[0] : (c16 == 1) ? se[1] : (c16 == 2) ? se[2] : se[3];
      srow[jl] = lrelu(a_i + blds[jl] + s);
    }
  }
  // col stats: reduce over q, stash per wave
  scs0 += __shfl_xor(scs0, 16, 64); scs0 += __shfl_xor(scs0, 32, 64);
  scss0 += __shfl_xor(scss0, 16, 64); scss0 += __shfl_xor(scss0, 32, 64);
  scs1 += __shfl_xor(scs1, 16, 64); scs1 += __shfl_xor(scs1, 32, 64);
  scss1 += __shfl_xor(scss1, 16, 64); scss1 += __shfl_xor(scss1, 32, 64);
  if (q == 0) {
    wred[0][w][c16] = scs0; wred[0][w][16 + c16] = scs1;
    wred[1][w][c16] = scss0; wred[1][w][16 + c16] = scss1;
  }
  __syncthreads();  // srow + wred complete
  if (tid < 64) {
    int half = tid >> 5, col = tid & 31;
    float v = 0.f;
#pragma unroll
    for (int ww = 0; ww < 8; ww++) v += wred[half][ww][col];
    ws[WS_PART + i * 64 + tid] = v;  // slot owned by this block, no atomics
  }
  // softmax (no max-subtraction: scores bounded small; shift-invariant)
  float p = __expf(srow[tid]);
  float sm = p;
#pragma unroll
  for (int off = 32; off >= 1; off >>= 1) sm += __shfl_xor(sm, off, 64);
  if (lane == 0) red[w] = sm;
  __syncthreads();
  float tot = red[0] + red[1] + red[2] + red[3] + red[4] + red[5] + red[6] + red[7];
  srow[tid] = p * (1.f / tot) * mlds[tid];  // att (same-wave reads below)
  // att @ xn : wave w covers j in [w*64, (w+1)*64)
  float accv = 0.f;
#pragma unroll 4
  for (int u = 0; u < 64; u++) {
    int j = w * 64 + u;
    accv += srow[j] * ws[WS_XN + j * 64 + lane];
  }
  nx[w][lane] = accv;
  __syncthreads();
  if (tid < 64) {
    float s = 0.f;
#pragma unroll
    for (int ww = 0; ww < 8; ww++) s += nx[ww][tid];
    ws[WS_NEWX + i * 64 + tid] = s;
  }
}

// ---------------- K3 (1 block): reduce edge partials -> esc/esh ----------------
__global__ void __launch_bounds__(512) k3(const float* __restrict__ bn_e_w,
                                          const float* __restrict__ bn_e_b,
                                          float* ws) {
  __shared__ float nx[8][64];
  int tid = threadIdx.x;
  int g = tid >> 6, c = tid & 63;
  float a = 0.f;
  for (int s = g; s < 512; s += 8) a += ws[WS_PART + s * 64 + c];
  nx[g][c] = a;
  __syncthreads();
  if (tid < 64) {
    float t = 0.f;
#pragma unroll
    for (int g2 = 0; g2 < 8; g2++) t += nx[g2][tid];
    nx[0][tid] = t;
  }
  __syncthreads();
  if (tid < 32) {
    float mean = nx[0][tid] * (1.f / 262144.f);
    float var = nx[0][tid + 32] * (1.f / 262144.f) - mean * mean;
    float s = bn_e_w[tid] * rsqrtf(fmaxf(var, 0.f) + EPS);
    ws[WS_ESC + tid] = s;
    ws[WS_ESH + tid] = bn_e_b[tid] - mean * s;
  }
}

// ---------------- K5: node BN (blocks 0..7, redundant stats) + edge BN apply ----------------
__global__ void __launch_bounds__(256) k5(const float* __restrict__ bn_n_w,
                                          const float* __restrict__ bn_n_b,
                                          const float* __restrict__ ws,
                                          float* __restrict__ out) {
  int blk = blockIdx.x, tid = threadIdx.x;
  if (blk < 8) {
    __shared__ float s1[4][64], s2[4][64], scl[64], sh[64];
    int c = tid & 63, g = tid >> 6;
    float a = 0.f, b = 0.f;
#pragma unroll 4
    for (int u = 0; u < 128; u++) {
      float v = ws[WS_NEWX + (g * 128 + u) * 64 + c];
      a += v;
      b += v * v;
    }
    s1[g][c] = a;
    s2[g][c] = b;
    __syncthreads();
    if (tid < 64) {
      float sum = s1[0][tid] + s1[1][tid] + s1[2][tid] + s1[3][tid];
      float ssq = s2[0][tid] + s2[1][tid] + s2[2][tid] + s2[3][tid];
      float mean = sum * (1.f / 512.f);
      float var = ssq * (1.f / 512.f) - mean * mean;
      float s = bn_n_w[tid] * rsqrtf(fmaxf(var, 0.f) + EPS);
      scl[tid] = s;
      sh[tid] = bn_n_b[tid] - mean * s;
    }
    __syncthreads();
#pragma unroll 4
    for (int u = 0; u < 16; u++) {
      int idx = blk * 4096 + u * 256 + tid;
      int c2 = idx & 63;
      out[idx] = ws[WS_NEWX + idx] * scl[c2] + sh[c2];
    }
  } else {
    const unsigned* ne32 = (const unsigned*)((const unsigned short*)ws + WSH_NE);
    int b4 = ((blk - 8) * 256 + tid) * 4;  // u32 index
    u32x4 raw = *(const u32x4*)(ne32 + b4);
    int e32 = (b4 >> 4) * 32;
    int cb = b4 & 15;  // 0,4,8,12
    f32x4 esc0 = *(const f32x4*)(ws + WS_ESC + cb);
    f32x4 esc1 = *(const f32x4*)(ws + WS_ESC + 16 + cb);
    f32x4 esh0 = *(const f32x4*)(ws + WS_ESH + cb);
    f32x4 esh1 = *(const f32x4*)(ws + WS_ESH + 16 + cb);
    f32x4 lo, hi;
#pragma unroll
    for (int u = 0; u < 4; u++) {
      lo[u] = bf2f((unsigned short)(raw[u] & 0xffffu)) * esc0[u] + esh0[u];
      hi[u] = bf2f((unsigned short)(raw[u] >> 16)) * esc1[u] + esh1[u];
    }
    float* oe = out + 32768;
    *(f32x4*)(oe + e32 + cb) = lo;
    *(f32x4*)(oe + e32 + 16 + cb) = hi;
  }
}

extern "C" void kernel_launch(void* const* d_in, const int* in_sizes, int n_in,
                              void* d_out, int out_size, void* d_ws, size_t ws_size,
                              hipStream_t stream) {
  const float* x = (const float*)d_in[0];
  const float* ea = (const float*)d_in[1];
  const int* mask = (const int*)d_in[2];
  const float* Wnu = (const float*)d_in[3];
  const float* bnu = (const float*)d_in[4];
  const float* Wh2 = (const float*)d_in[5];
  const float* bh2 = (const float*)d_in[6];
  const float* Weo = (const float*)d_in[7];
  const float* beo = (const float*)d_in[8];
  const float* ev = (const float*)d_in[9];
  const float* bnw = (const float*)d_in[10];
  const float* bnb = (const float*)d_in[11];
  const float* bew = (const float*)d_in[12];
  const float* beb = (const float*)d_in[13];
  float* ws = (float*)d_ws;
  float* out = (float*)d_out;

  k1<<<168, 256, 0, stream>>>(x, Wnu, bnu, Wh2, bh2, Weo, ev, ws);
  k2<<<512, 512, 0, stream>>>(ea, mask, beo, ev, ws);
  k3<<<1, 512, 0, stream>>>(bew, beb, ws);
  k5<<<4104, 256, 0, stream>>>(bnw, bnb, ws, out);
}

// Round 9
// 162.053 us; speedup vs baseline: 1.1824x; 1.1670x over previous
//
#include <hip/hip_runtime.h>

#define SLOPE 0.1f
#define EPS 1e-5f

typedef __bf16 bf16x8 __attribute__((ext_vector_type(8)));
typedef unsigned short u16x8 __attribute__((ext_vector_type(8)));
typedef float f32x4 __attribute__((ext_vector_type(4)));
typedef unsigned u32x4 __attribute__((ext_vector_type(4)));

// ---- workspace layout ----
// float offsets on (float*)ws:
#define WS_ESC 0        // 32 : edge BN scale (written by k3 blk 512)
#define WS_ESH 32       // 32 : edge BN shift
#define WS_A 64         // 512 : dot(xn_i, ev[0:64])
#define WS_B 576        // 512 : dot(xn_j, ev[96:160])
#define WS_XN 1088      // 512*64 post-lrelu node feats
#define WS_NEWX 33856   // 512*64 pre-BN new_x
#define WS_P1B 66624    // 512*80 : b_h2[k] + x_i . W_h2[k][0:64]
#define WS_SC 107584    // 512*512 scores (post-lrelu, pre-softmax)
#define WS_PART 369728  // 512 slots x 64 : edge BN partials (zeroed by k1)
// u16 offsets on (unsigned short*)ws (float end 402496 -> u16 804992).
// Weight tables FRAG-MAJOR: element (t, lane l, jj) at [t*512 + l*8 + jj],
// i.e. MFMA B-frag value: n = t*16 + (l&15), k = (l>>4)*8 + jj.
#define WSH_WB 804992   // 2*2560 : GEMM1 B chunks 0,1 (W_h2 cols 64:96, 96:128)
#define WSH_WB2 810112  // 2560   : GEMM1 B chunk 2    (W_h2 cols 128:160)
#define WSH_WO 812672   // 3072   : GEMM2 B (W_eo, k padded to 96)
#define WSH_XB 815744   // 512*64 bf16 copy of x (row-major)
#define WSH_NE 848512   // 262144 edges * 16 u32 (col c | col c+16), bf16 packed

__device__ __forceinline__ float lrelu(float v) { return v > 0.f ? v : SLOPE * v; }
__device__ __forceinline__ unsigned short f2bf(float f) {
  unsigned x = __float_as_uint(f);
  return (unsigned short)((x + 0x7fffu + ((x >> 16) & 1u)) >> 16);
}
__device__ __forceinline__ float bf2f(unsigned short u) {
  return __uint_as_float(((unsigned)u) << 16);
}

// ---------------- K1 ----------------
// blocks 0..127 : xn + a/b scalars + bf16 copies (x, frag-major weights) + zero PART
// blocks 128..167 : P1 via MFMA  (M=512 x N=80, K=64)
__global__ void __launch_bounds__(256) k1(const float* __restrict__ x,
                                          const float* __restrict__ W_nu,
                                          const float* __restrict__ b_nu,
                                          const float* __restrict__ W_h2,
                                          const float* __restrict__ b_h2,
                                          const float* __restrict__ W_eo,
                                          const float* __restrict__ ev,
                                          float* ws) {
  int blk = blockIdx.x;
  int tid = threadIdx.x;
  unsigned short* wsh = (unsigned short*)ws;
  if (blk < 128) {
    __shared__ float wlds[64 * 65];
#pragma unroll
    for (int it = 0; it < 16; it++) {
      int idx = it * 256 + tid;
      wlds[(idx >> 6) * 65 + (idx & 63)] = W_nu[idx];
    }
    int gid = blk * 256 + tid;  // 0..32767
    wsh[WSH_XB + gid] = f2bf(x[gid]);
    ws[WS_PART + gid] = 0.f;
    if (gid < 5120) {
      int c = gid / 2560, r = gid - c * 2560;
      int t = r >> 9, l = (r >> 3) & 63, jj = r & 7;
      int n = t * 16 + (l & 15);
      int k = (l >> 4) * 8 + jj + c * 32;
      wsh[WSH_WB + gid] = f2bf(W_h2[n * 160 + 64 + k]);
    } else if (gid < 7680) {
      int idx = gid - 5120;
      int t = idx >> 9, l = (idx >> 3) & 63, jj = idx & 7;
      int n = t * 16 + (l & 15);
      int k = (l >> 4) * 8 + jj;
      wsh[WSH_WB2 + idx] = f2bf(W_h2[n * 160 + 128 + k]);
    } else if (gid < 10752) {
      int idx = gid - 7680;
      int t2 = idx / 1536, r2 = idx - t2 * 1536;
      int s = r2 >> 9, l = (r2 >> 3) & 63, jj = r2 & 7;
      int n = t2 * 16 + (l & 15);
      int k = s * 32 + (l >> 4) * 8 + jj;
      wsh[WSH_WO + idx] = (k < 80) ? f2bf(W_eo[n * 80 + k]) : (unsigned short)0;
    }
    __syncthreads();
    int i = blk * 4 + (tid >> 6);
    int c = tid & 63;
    float acc = b_nu[c];
    const float* xr = x + i * 64;
#pragma unroll 8
    for (int k = 0; k < 64; k++) acc += xr[k] * wlds[c * 65 + k];
    float xnv = lrelu(acc);
    ws[WS_XN + i * 64 + c] = xnv;
    float va = xnv * ev[c];
    float vb = xnv * ev[96 + c];
#pragma unroll
    for (int off = 32; off >= 1; off >>= 1) {
      va += __shfl_xor(va, off, 64);
      vb += __shfl_xor(vb, off, 64);
    }
    if (c == 0) { ws[WS_A + i] = va; ws[WS_B + i] = vb; }
  } else {
    // MFMA P1-GEMM: block covers 64 rows (bm) x 16 cols (bn) of N=80
    int b2 = blk - 128;             // 0..39
    int bm = b2 & 7, bn = b2 >> 3;  // M-tile of 64, N-tile of 16
    int wave = tid >> 6, lane = tid & 63;
    int c16 = lane & 15, q = lane >> 4;
    int n = bn * 16 + c16;  // 0..79
    const float* wrow = W_h2 + n * 160;
    int mrow = bm * 64 + wave * 16 + c16;
    bf16x8 bfr[2], afr[2];
#pragma unroll
    for (int ks = 0; ks < 2; ks++) {
      const float* bs = wrow + ks * 32 + q * 8;
      const float* as = x + mrow * 64 + ks * 32 + q * 8;
      u16x8 ub, ua;
#pragma unroll
      for (int jj = 0; jj < 8; jj++) { ub[jj] = f2bf(bs[jj]); ua[jj] = f2bf(as[jj]); }
      bfr[ks] = __builtin_bit_cast(bf16x8, ub);
      afr[ks] = __builtin_bit_cast(bf16x8, ua);
    }
    float bias = b_h2[n];
    f32x4 acc = {bias, bias, bias, bias};
    acc = __builtin_amdgcn_mfma_f32_16x16x32_bf16(afr[0], bfr[0], acc, 0, 0, 0);
    acc = __builtin_amdgcn_mfma_f32_16x16x32_bf16(afr[1], bfr[1], acc, 0, 0, 0);
#pragma unroll
    for (int r = 0; r < 4; r++) {
      int mm = bm * 64 + wave * 16 + q * 4 + r;
      ws[WS_P1B + mm * 80 + n] = acc[r];
    }
  }
}

// ---------------- K2: edge MLP (K=96 MFMA) + scores + BN-stat partials ----------------
// block = 64 edges (one i, 64 consecutive j); 4 waves x one 16-edge tile each.
// Weights staged once per block into LDS (frag-major, conflict-free b128 reads).
__global__ void __launch_bounds__(256) k2(const float* __restrict__ ea,
                                          const int* __restrict__ mask,
                                          const float* __restrict__ b_eo,
                                          const float* __restrict__ ev,
                                          float* ws) {
  __shared__ unsigned short wlds[10752];  // [ch0|ch1|ch2|wo] frag-major
  __shared__ unsigned short ht[64 * 104];
  __shared__ float p1s[80];
  __shared__ float wred[2][4][32];
  int tid = threadIdx.x;
  int w = tid >> 6, lane = tid & 63;
  int c16 = lane & 15, q = lane >> 4;
  int blk = blockIdx.x;
  int i = blk >> 3, j0 = (blk & 7) << 6;
  int jb = j0 + w * 16;
  const unsigned short* wsh = (const unsigned short*)ws;
  unsigned* ne32 = (unsigned*)((unsigned short*)ws + WSH_NE);

  // stage weights: 1344 x 16B contiguous
#pragma unroll
  for (int it = 0; it < 6; it++) {
    int idx = it * 256 + tid;
    if (idx < 1344) *(u16x8*)&wlds[idx * 8] = *(const u16x8*)(wsh + WSH_WB + idx * 8);
  }
  if (tid < 80) p1s[tid] = ws[WS_P1B + i * 80 + tid];
  float beo0 = b_eo[c16], beo1 = b_eo[16 + c16];
  float eve0 = ev[64 + c16], eve1 = ev[80 + c16];
  float a_i = ws[WS_A + i];
  __syncthreads();

  // A-frags: chunk0 = ea (f2bf), chunk1/2 = bf16 x_j (direct 16B loads)
  bf16x8 af0;
  {
    const float* src = ea + (i * 512 + jb + c16) * 32 + q * 8;
    u16x8 u;
#pragma unroll
    for (int jj = 0; jj < 8; jj++) u[jj] = f2bf(src[jj]);
    af0 = __builtin_bit_cast(bf16x8, u);
  }
  bf16x8 af1 = __builtin_bit_cast(
      bf16x8, *(const u16x8*)(wsh + WSH_XB + (jb + c16) * 64 + q * 8));
  bf16x8 af2 = __builtin_bit_cast(
      bf16x8, *(const u16x8*)(wsh + WSH_XB + (jb + c16) * 64 + 32 + q * 8));

  f32x4 acc[5];
#pragma unroll
  for (int t = 0; t < 5; t++) {
    float p1v = p1s[t * 16 + c16];
    acc[t] = {p1v, p1v, p1v, p1v};
  }
#pragma unroll
  for (int t = 0; t < 5; t++) {
    bf16x8 wb = __builtin_bit_cast(bf16x8, *(const u16x8*)&wlds[t * 512 + lane * 8]);
    acc[t] = __builtin_amdgcn_mfma_f32_16x16x32_bf16(af0, wb, acc[t], 0, 0, 0);
  }
#pragma unroll
  for (int t = 0; t < 5; t++) {
    bf16x8 wb =
        __builtin_bit_cast(bf16x8, *(const u16x8*)&wlds[2560 + t * 512 + lane * 8]);
    acc[t] = __builtin_amdgcn_mfma_f32_16x16x32_bf16(af1, wb, acc[t], 0, 0, 0);
  }
#pragma unroll
  for (int t = 0; t < 5; t++) {
    bf16x8 wb =
        __builtin_bit_cast(bf16x8, *(const u16x8*)&wlds[5120 + t * 512 + lane * 8]);
    acc[t] = __builtin_amdgcn_mfma_f32_16x16x32_bf16(af2, wb, acc[t], 0, 0, 0);
  }
  // lrelu -> ht (same-wave 16-row stripe; no barrier needed)
#pragma unroll
  for (int t = 0; t < 5; t++)
#pragma unroll
    for (int r = 0; r < 4; r++)
      ht[(w * 16 + q * 4 + r) * 104 + t * 16 + c16] = f2bf(lrelu(acc[t][r]));

  // GEMM2: ne = h @ W_eo^T
  f32x4 acc2[2] = {{0.f, 0.f, 0.f, 0.f}, {0.f, 0.f, 0.f, 0.f}};
  int hrow = w * 16 + c16;
#pragma unroll
  for (int s = 0; s < 3; s++) {
    int kk = s * 32 + q * 8;
    u16x8 hb = {0, 0, 0, 0, 0, 0, 0, 0};
    if (kk < 80) hb = *(const u16x8*)&ht[hrow * 104 + kk];
    bf16x8 ha = __builtin_bit_cast(bf16x8, hb);
    bf16x8 wo0 =
        __builtin_bit_cast(bf16x8, *(const u16x8*)&wlds[7680 + s * 512 + lane * 8]);
    bf16x8 wo1 = __builtin_bit_cast(
        bf16x8, *(const u16x8*)&wlds[7680 + 1536 + s * 512 + lane * 8]);
    acc2[0] = __builtin_amdgcn_mfma_f32_16x16x32_bf16(ha, wo0, acc2[0], 0, 0, 0);
    acc2[1] = __builtin_amdgcn_mfma_f32_16x16x32_bf16(ha, wo1, acc2[1], 0, 0, 0);
  }

  // epilogue: bias, lrelu, mask; packed bf16 store; col stats; scores
  float scs0 = 0.f, scss0 = 0.f, scs1 = 0.f, scss1 = 0.f;
  float se[4];
#pragma unroll
  for (int r = 0; r < 4; r++) {
    int m = i * 512 + jb + q * 4 + r;
    float mf = mask[m] ? 1.f : 0.f;
    float v0 = lrelu(acc2[0][r] + beo0) * mf;
    float v1 = lrelu(acc2[1][r] + beo1) * mf;
    scs0 += v0; scss0 += v0 * v0;
    scs1 += v1; scss1 += v1 * v1;
    ne32[m * 16 + c16] = (unsigned)f2bf(v0) | ((unsigned)f2bf(v1) << 16);
    float s = v0 * eve0 + v1 * eve1;
#pragma unroll
    for (int off = 8; off >= 1; off >>= 1) s += __shfl_xor(s, off, 64);
    se[r] = s;
  }
  if (c16 < 4) {
    int j = jb + q * 4 + c16;
    float s = (c16 == 0) ? se[0] : (c16 == 1) ? se[1] : (c16 == 2) ? se[2] : se[3];
    ws[WS_SC + i * 512 + j] = lrelu(a_i + ws[WS_B + j] + s);
  }
  // col stats: reduce over q, stash per wave, then striped atomics (8-way)
  scs0 += __shfl_xor(scs0, 16, 64); scs0 += __shfl_xor(scs0, 32, 64);
  scss0 += __shfl_xor(scss0, 16, 64); scss0 += __shfl_xor(scss0, 32, 64);
  scs1 += __shfl_xor(scs1, 16, 64); scs1 += __shfl_xor(scs1, 32, 64);
  scss1 += __shfl_xor(scss1, 16, 64); scss1 += __shfl_xor(scss1, 32, 64);
  if (q == 0) {
    wred[0][w][c16] = scs0; wred[0][w][16 + c16] = scs1;
    wred[1][w][c16] = scss0; wred[1][w][16 + c16] = scss1;
  }
  __syncthreads();
  if (tid < 64) {
    int half = tid >> 5, col = tid & 31;
    float v = wred[half][0][col] + wred[half][1][col] + wred[half][2][col] +
              wred[half][3][col];
    atomicAdd(&ws[WS_PART + (blk >> 3) * 64 + tid], v);
  }
}

// ---------------- K3: blocks 0..511 softmax+att@xn; blk 512 reduces partials ----------------
__global__ void __launch_bounds__(512) k3(const int* __restrict__ mask,
                                          const float* __restrict__ bn_e_w,
                                          const float* __restrict__ bn_e_b,
                                          float* ws) {
  __shared__ float att[512];
  __shared__ float red[8];
  __shared__ float nx[8][64];
  int i = blockIdx.x, tid = threadIdx.x;
  int wave = tid >> 6, lane = tid & 63;
  if (i == 512) {
    int g = tid >> 6, c = tid & 63;
    float a = 0.f;
    for (int s = g; s < 512; s += 8) a += ws[WS_PART + s * 64 + c];
    nx[g][c] = a;
    __syncthreads();
    if (tid < 64) {
      float t = 0.f;
#pragma unroll
      for (int g2 = 0; g2 < 8; g2++) t += nx[g2][tid];
      att[tid] = t;
    }
    __syncthreads();
    if (tid < 32) {
      float mean = att[tid] * (1.f / 262144.f);
      float var = att[tid + 32] * (1.f / 262144.f) - mean * mean;
      float s = bn_e_w[tid] * rsqrtf(fmaxf(var, 0.f) + EPS);
      ws[WS_ESC + tid] = s;
      ws[WS_ESH + tid] = bn_e_b[tid] - mean * s;
    }
    return;
  }
  // softmax (no max-subtraction: scores bounded small; shift-invariant)
  float p = __expf(ws[WS_SC + i * 512 + tid]);
  float sm = p;
#pragma unroll
  for (int off = 32; off >= 1; off >>= 1) sm += __shfl_xor(sm, off, 64);
  if (lane == 0) red[wave] = sm;
  __syncthreads();
  float tot = red[0] + red[1] + red[2] + red[3] + red[4] + red[5] + red[6] + red[7];
  att[tid] = p * (1.f / tot) * (mask[i * 512 + tid] ? 1.f : 0.f);
  __syncthreads();
  // new_x[i][c] = sum_j att[j]*xn[j][c]; wave w covers j in [w*64, (w+1)*64)
  int c = lane;
  const float* xn = ws + WS_XN;
  float accv = 0.f;
#pragma unroll 4
  for (int u = 0; u < 64; u++) {
    int j = wave * 64 + u;
    accv += att[j] * xn[j * 64 + c];
  }
  nx[wave][c] = accv;
  __syncthreads();
  if (tid < 64) {
    float s = 0.f;
#pragma unroll
    for (int w = 0; w < 8; w++) s += nx[w][tid];
    ws[WS_NEWX + i * 64 + tid] = s;
  }
}

// ---------------- K5: node BN (blocks 0..7, redundant stats) + edge BN apply ----------------
__global__ void __launch_bounds__(256) k5(const float* __restrict__ bn_n_w,
                                          const float* __restrict__ bn_n_b,
                                          const float* __restrict__ ws,
                                          float* __restrict__ out) {
  int blk = blockIdx.x, tid = threadIdx.x;
  if (blk < 8) {
    __shared__ float s1[4][64], s2[4][64], scl[64], sh[64];
    int c = tid & 63, g = tid >> 6;
    float a = 0.f, b = 0.f;
#pragma unroll 4
    for (int u = 0; u < 128; u++) {
      float v = ws[WS_NEWX + (g * 128 + u) * 64 + c];
      a += v;
      b += v * v;
    }
    s1[g][c] = a;
    s2[g][c] = b;
    __syncthreads();
    if (tid < 64) {
      float sum = s1[0][tid] + s1[1][tid] + s1[2][tid] + s1[3][tid];
      float ssq = s2[0][tid] + s2[1][tid] + s2[2][tid] + s2[3][tid];
      float mean = sum * (1.f / 512.f);
      float var = ssq * (1.f / 512.f) - mean * mean;
      float s = bn_n_w[tid] * rsqrtf(fmaxf(var, 0.f) + EPS);
      scl[tid] = s;
      sh[tid] = bn_n_b[tid] - mean * s;
    }
    __syncthreads();
#pragma unroll 4
    for (int u = 0; u < 16; u++) {
      int idx = blk * 4096 + u * 256 + tid;
      int c2 = idx & 63;
      out[idx] = ws[WS_NEWX + idx] * scl[c2] + sh[c2];
    }
  } else {
    const unsigned* ne32 = (const unsigned*)((const unsigned short*)ws + WSH_NE);
    int b4 = ((blk - 8) * 256 + tid) * 4;  // u32 index
    u32x4 raw = *(const u32x4*)(ne32 + b4);
    int e32 = (b4 >> 4) * 32;
    int cb = b4 & 15;  // 0,4,8,12
    f32x4 esc0 = *(const f32x4*)(ws + WS_ESC + cb);
    f32x4 esc1 = *(const f32x4*)(ws + WS_ESC + 16 + cb);
    f32x4 esh0 = *(const f32x4*)(ws + WS_ESH + cb);
    f32x4 esh1 = *(const f32x4*)(ws + WS_ESH + 16 + cb);
    f32x4 lo, hi;
#pragma unroll
    for (int u = 0; u < 4; u++) {
      lo[u] = bf2f((unsigned short)(raw[u] & 0xffffu)) * esc0[u] + esh0[u];
      hi[u] = bf2f((unsigned short)(raw[u] >> 16)) * esc1[u] + esh1[u];
    }
    float* oe = out + 32768;
    *(f32x4*)(oe + e32 + cb) = lo;
    *(f32x4*)(oe + e32 + 16 + cb) = hi;
  }
}

extern "C" void kernel_launch(void* const* d_in, const int* in_sizes, int n_in,
                              void* d_out, int out_size, void* d_ws, size_t ws_size,
                              hipStream_t stream) {
  const float* x = (const float*)d_in[0];
  const float* ea = (const float*)d_in[1];
  const int* mask = (const int*)d_in[2];
  const float* Wnu = (const float*)d_in[3];
  const float* bnu = (const float*)d_in[4];
  const float* Wh2 = (const float*)d_in[5];
  const float* bh2 = (const float*)d_in[6];
  const float* Weo = (const float*)d_in[7];
  const float* beo = (const float*)d_in[8];
  const float* ev = (const float*)d_in[9];
  const float* bnw = (const float*)d_in[10];
  const float* bnb = (const float*)d_in[11];
  const float* bew = (const float*)d_in[12];
  const float* beb = (const float*)d_in[13];
  float* ws = (float*)d_ws;
  float* out = (float*)d_out;

  k1<<<168, 256, 0, stream>>>(x, Wnu, bnu, Wh2, bh2, Weo, ev, ws);
  k2<<<4096, 256, 0, stream>>>(ea, mask, beo, ev, ws);
  k3<<<513, 512, 0, stream>>>(mask, bew, beb, ws);
  k5<<<4104, 256, 0, stream>>>(bnw, bnb, ws, out);
}